// Round 4
// baseline (87.454 us; speedup 1.0000x reference)
//
#include <hip/hip_runtime.h>

typedef float f32x4 __attribute__((ext_vector_type(4)));
typedef int   i32x4 __attribute__((ext_vector_type(4)));
typedef int   i32x8 __attribute__((ext_vector_type(8)));
typedef unsigned short ushort_t;

#define T_LEN 128
#define BATCH 64
#define M_TOK 8192   // BATCH * T_LEN
#define HDIM  128
#define SQRT_LOG2E 1.2011224087864498f  // (s*xi).(s*xj) = log2(e)*xi.xj

// 2^t Taylor deg-4 restructured: 2^t ~= 1 + t*q(t),
// q(t) = C1 + t*(C2 + t*(C3 + t*C4)); the "+1"s are folded into
// accumulator inits (8.0f per lane row-side, +256.0f per col flush).
#define P_C1 0.6931471806f
#define P_C2 0.2402265070f
#define P_C3 0.0555041087f
#define P_C4 0.0096181291f

// Fragment-major layout for 16x16x128 f8f6f4 MFMA:
// xsw[T][quad][col][32B]  (strides 2048 / 512 / 32 bytes)
// = bytes [quad*32, quad*32+32) of token (16*T + col), fp8 e4m3, pre-scaled.

// Kernel A: 2048 blocks x 256 thr; wave w handles token row blockIdx*4+w.
// Also zeroes ns[i] (stream order makes the zero visible to negsum).
__global__ __launch_bounds__(256) void prep_kernel(const float* __restrict__ hs,
                                                   unsigned char* __restrict__ xsw,
                                                   float* __restrict__ pos,
                                                   float* __restrict__ ns,
                                                   unsigned int* __restrict__ counter) {
    int wave = threadIdx.x >> 6;
    int lane = threadIdx.x & 63;
    int i = blockIdx.x * 4 + wave;
    int t = i & (T_LEN - 1);
    const float* row = hs + (size_t)i * HDIM;
    float2 x = *(const float2*)(row + 2 * lane);
    unsigned int pk = __builtin_amdgcn_cvt_pk_fp8_f32(x.x * SQRT_LOG2E,
                                                      x.y * SQRT_LOG2E, 0, false);
    {
        int Ti  = i >> 4;
        int c   = i & 15;
        int qd  = lane >> 4;            // (2*lane) / 32
        int off = (2 * lane) & 31;      // within the 32B chunk (even)
        *(ushort_t*)(xsw + (size_t)Ti * 2048 + qd * 512 + c * 32 + off) = (ushort_t)pk;
    }
    float acc = 0.f;
    if (t > 0) {
        float2 p = *(const float2*)(row - HDIM + 2 * lane);
        acc += x.x * p.x + x.y * p.y;
    }
    if (t < T_LEN - 1) {
        float2 n = *(const float2*)(row + HDIM + 2 * lane);
        acc += x.x * n.x + x.y * n.y;
    }
    for (int m = 32; m; m >>= 1) acc += __shfl_xor(acc, m);
    if (lane == 0) { pos[i] = acc; ns[i] = 0.f; }
    if (blockIdx.x == 0 && threadIdx.x == 0) counter[0] = 0u;
}

__device__ inline i32x8 load_frag32(const unsigned char* p) {
    i32x4 lo = *(const i32x4*)p;
    i32x4 hi = *(const i32x4*)(p + 16);
    return __builtin_shufflevector(lo, hi, 0, 1, 2, 3, 4, 5, 6, 7);
}

// Kernel B (R13): SYMMETRIC halving. exp(Gram) is symmetric, so col-sums
// equal row-sums: compute only block-pairs (rg, cs) with cs >= rg.
//  - grid (32, 32, 2): x=rg (256 rows), y=cs (256 cols), z=jhalf
//    (8 of the 16 col-tiles). cs<rg blocks exit immediately (992 empties,
//    ~free); 1056 real half-blocks ~ 4.1/CU, load-balanced.
//  - every block: row-sums as before (atomicAdd per row, "+1"s folded as
//    init 8.0f/lane = 8 iters).
//  - off-diagonal blocks additionally scatter col-sums: per iter, per-lane
//    sum of its 16 row-terms (csv fma-accumulated), 2x shfl_xor quad
//    reduce, staged in LDS csum[wave][jl][col]; one 128-atomic flush at
//    the end (+256.0f = the 256 folded "+1"s of that column's rows).
//  - diagonal blocks (cs==rg) compute their full 256x256, row-sums only.
// Total MFMA/poly/load work: 528/1024 = 51.6% of R12.
__global__ __launch_bounds__(256) void negsum_kernel(const unsigned char* __restrict__ xsw,
                                                     float* __restrict__ ns) {
    int rg = blockIdx.x;                   // row group (256 rows)
    int cs = blockIdx.y;                   // col group (256 cols)
    if (cs < rg) return;                   // lower triangle: covered by symmetry
    __shared__ float csum[512];            // [wave][jl][col]
    int jh   = blockIdx.z;                 // which 8 of the 16 col-tiles
    int tid  = threadIdx.x;
    int wave = tid >> 6;
    int lane = tid & 63;
    int col  = lane & 15;
    int quad = lane >> 4;
    int laneoff = quad * 512 + col * 32;
    int rot  = rg & 7;                     // stagger same-cs readers
    const int sc = 0x7F7F7F7F;             // E8M0 scale 127 -> x1.0
    const bool offdiag = (cs > rg);        // block-uniform

    // A frags: row tiles rg*16 + wave*4 .. +3 (loop-invariant, 8 VGPRs each)
    int rowtile = rg * 16 + wave * 4;
    i32x8 afr[4];
    #pragma unroll
    for (int rb = 0; rb < 4; ++rb)
        afr[rb] = load_frag32(xsw + (size_t)(rowtile + rb) * 2048 + laneoff);

    f32x4 rsv[4];
    #pragma unroll
    for (int rb = 0; rb < 4; ++rb) rsv[rb] = (f32x4){8.f, 8.f, 8.f, 8.f};

    const unsigned char* bptr = xsw + (size_t)(cs * 16 + jh * 8) * 2048 + laneoff;

    i32x8 bf[4];                           // 4-deep prefetch ring
    #pragma unroll
    for (int p = 0; p < 4; ++p)
        bf[p] = load_frag32(bptr + (size_t)((rot + p) & 7) * 2048);

    #pragma unroll
    for (int i = 0; i < 8; ++i) {
        int slot = i & 3;
        f32x4 d[4];
        #pragma unroll
        for (int rb = 0; rb < 4; ++rb)
            d[rb] = __builtin_amdgcn_mfma_scale_f32_16x16x128_f8f6f4(
                afr[rb], bf[slot], (f32x4){0.f, 0.f, 0.f, 0.f}, 0, 0, 0, sc, 0, sc);
        if (i + 4 < 8)
            bf[slot] = load_frag32(bptr + (size_t)((rot + i + 4) & 7) * 2048);
        f32x4 csv = (f32x4){0.f, 0.f, 0.f, 0.f};
        #pragma unroll
        for (int rb = 0; rb < 4; ++rb) {
            f32x4 v = d[rb];               // log2(e) * x_row . x_col
            f32x4 q = v * P_C4 + P_C3;     // deg-3 Horner for q(t)
            q = q * v + P_C2;
            q = q * v + P_C1;
            rsv[rb] = q * v + rsv[rb];     // row accum: exp ~= 1 + v*q
            csv     = q * v + csv;         // col accum (this iter's col-tile)
        }
        // col-sums for tile jl=(rot+i)&7: per-lane 16 rows -> 4 quads -> 64 rows
        float cp = csv[0] + csv[1] + csv[2] + csv[3];
        cp += __shfl_xor(cp, 16);
        cp += __shfl_xor(cp, 32);
        if (quad == 0) csum[wave * 128 + ((rot + i) & 7) * 16 + col] = cp;
    }

    // row sums: reduce across the 16 col-lanes within each quad group
    #pragma unroll
    for (int m = 1; m < 16; m <<= 1)
        #pragma unroll
        for (int rb = 0; rb < 4; ++rb)
            #pragma unroll
            for (int r = 0; r < 4; ++r)
                rsv[rb][r] += __shfl_xor(rsv[rb][r], m);

    if (col == 0) {
        #pragma unroll
        for (int rb = 0; rb < 4; ++rb)
            #pragma unroll
            for (int r = 0; r < 4; ++r)
                atomicAdd(ns + (size_t)(rg * 256 + wave * 64 + rb * 16 + quad * 4 + r),
                          rsv[rb][r]);
    }

    // col sums by symmetry: only off-diagonal blocks scatter to cols
    if (offdiag) {
        __syncthreads();                   // block-uniform branch: safe
        if (tid < 128) {
            float s = csum[tid] + csum[128 + tid] + csum[256 + tid] + csum[384 + tid];
            atomicAdd(ns + (size_t)cs * 256 + jh * 128 + tid, s + 256.0f);
        }
    }
}

// Kernel C (fused): one block per batch; last finishing block reduces bpart.
__global__ __launch_bounds__(128) void fin_kernel(const float* __restrict__ ns,
                                                  const float* __restrict__ pos,
                                                  const int* __restrict__ dia,
                                                  float* __restrict__ bpart,
                                                  unsigned int* __restrict__ counter,
                                                  float* __restrict__ out) {
    __shared__ float s2[2];
    __shared__ int slast;
    int b = blockIdx.x;
    int t = threadIdx.x;
    int len = dia[b];
    int i = b * T_LEN + t;
    float acc = (t < len - 1) ? (__logf(ns[i]) - pos[i]) : 0.f;
    for (int m = 32; m; m >>= 1) acc += __shfl_xor(acc, m);
    if ((t & 63) == 0) s2[t >> 6] = acc;
    __syncthreads();
    if (t == 0) {
        bpart[b] = s2[0] + s2[1];
        __threadfence();                               // release bpart[b]
        slast = (atomicAdd(counter, 1u) == BATCH - 1);
    }
    __syncthreads();
    if (slast && t < 64) {
        __threadfence();                               // acquire others' bpart
        float s = bpart[t];
        int c = dia[t] - 1;
        for (int m = 32; m; m >>= 1) {
            s += __shfl_xor(s, m);
            c += __shfl_xor(c, m);
        }
        if (t == 0) out[0] = s / (float)c;
    }
}

extern "C" void kernel_launch(void* const* d_in, const int* in_sizes, int n_in,
                              void* d_out, int out_size, void* d_ws, size_t ws_size,
                              hipStream_t stream) {
    const float* hs  = (const float*)d_in[0];
    // d_in[1] = mask (implied by dia_lens; unused)
    const int*   dia = (const int*)d_in[2];
    float* out = (float*)d_out;

    unsigned char* xsw = (unsigned char*)d_ws;                         // 1 MB fragment-major fp8
    float* pos    = (float*)((char*)d_ws + 1048576);                   // 32 KB
    float* ns     = (float*)((char*)d_ws + 1048576 + 32768);           // 32 KB accumulated negsum
    float* bpart  = (float*)((char*)d_ws + 1048576 + 65536);           // 256 B
    unsigned int* counter = (unsigned int*)((char*)d_ws + 1048576 + 65536 + 256);

    prep_kernel<<<M_TOK / 4, 256, 0, stream>>>(hs, xsw, pos, ns, counter);
    negsum_kernel<<<dim3(32, 32, 2), 256, 0, stream>>>(xsw, ns);
    fin_kernel<<<BATCH, 128, 0, stream>>>(ns, pos, dia, bpart, counter, out);
}